// Round 5
// baseline (277.611 us; speedup 1.0000x reference)
//
#include <hip/hip_runtime.h>
#include <math.h>

// Problem constants
#define BB 2

// ws layout (float offsets)
#define WS_PPART 0         // 2*128*256 pool partials
#define WS_GLOB  66048     // 2*256
#define WS_KVP   66560     // 16*32*1024 KV partials
#define WS_KSP   590848    // 16*32*32 Ksum partials
#define WS_KVT   607232    // bf16 KV_aug: 16*48*32 ushort
#define WS_WFP   619520    // bf16 Wf k-grouped [64][256][8]: 131072 ushort
#define WS_L1T   685056    // bf16 l1 panels [8][4][256][8]: 65536 ushort
#define WS_L2T   717824
#define WS_KWT   750592
#define WS_VWT   783360

typedef __attribute__((ext_vector_type(8))) short short8v;
typedef __attribute__((ext_vector_type(4))) float f32x4;

__device__ __forceinline__ ushort f2bf(float x) {
    union { float f; unsigned int u; } v; v.f = x;
    unsigned int u = v.u;
    unsigned int r = (u + 0x7fffu + ((u >> 16) & 1u)) >> 16;
    return (ushort)r;
}

__device__ __forceinline__ float bf2f(ushort x) {
    union { float f; unsigned int u; } v;
    v.u = ((unsigned int)x) << 16;
    return v.f;
}

// packed f32x2 -> bf16x2 (RNE), 1 VALU op
__device__ __forceinline__ unsigned int cvtpk(float lo, float hi) {
    unsigned int d;
    asm("v_cvt_pk_bf16_f32 %0, %1, %2" : "=v"(d) : "v"(lo), "v"(hi));
    return d;
}

// async global->LDS, 16B per lane; lds base must be wave-uniform
__device__ __forceinline__ void gload16(const void* g, void* l) {
    __builtin_amdgcn_global_load_lds(
        (const __attribute__((address_space(1))) unsigned int*)g,
        (__attribute__((address_space(3))) unsigned int*)l, 16, 0, 0);
}

// ---------------- merged prep ----------------
// blocks 0..1023: tile l1/l2/kw/vw: (k,n) -> ushort idx (k>>5)*8192 + ((k>>3)&3)*2048 + n*8 + (k&7)
// blocks 1024..1535: Wf = mh @ qw, k-grouped: (g,n) -> (g>>3)*2048 + n*8 + (g&7)
// blocks 1536..1791: pool partials
__global__ __launch_bounds__(256) void k_prep(const float* __restrict__ l1w, const float* __restrict__ l2w,
                                              const float* __restrict__ kw, const float* __restrict__ vw,
                                              const float* __restrict__ mh, const float* __restrict__ qw,
                                              const float* __restrict__ key,
                                              ushort* __restrict__ t0, ushort* __restrict__ t1,
                                              ushort* __restrict__ t2, ushort* __restrict__ t3,
                                              ushort* __restrict__ wfp, float* __restrict__ ppart) {
    int blk = blockIdx.x, t = threadIdx.x;
    if (blk < 1024) {
        int mat = blk >> 8, k = blk & 255, n = t;
        const float* w = mat == 0 ? l1w : mat == 1 ? l2w : mat == 2 ? kw : vw;
        ushort* o = mat == 0 ? t0 : mat == 1 ? t1 : mat == 2 ? t2 : t3;
        o[(size_t)(k >> 5) * 8192 + (size_t)((k >> 3) & 3) * 2048 + n * 8 + (k & 7)] = f2bf(w[k * 256 + n]);
    } else if (blk < 1536) {
        __shared__ float mr[256];
        int g = blk - 1024;
        mr[t] = mh[g * 256 + t];
        __syncthreads();
        float acc = 0.f;
        for (int k = 0; k < 256; k++) acc += mr[k] * qw[k * 256 + t];
        wfp[(size_t)(g >> 3) * 2048 + t * 8 + (g & 7)] = f2bf(acc);
    } else {
        int p = blk - 1536;
        int b = p >> 7, ci = p & 127;
        float acc = 0.f;
        for (int q = 0; q < 128; q++) {
            size_t idx = ((size_t)b * 65536 + (size_t)(2 * ci + 1) * 256 + (2 * q + 1)) * 256 + t;
            acc += key[idx];
        }
        ppart[(size_t)p * 256 + t] = acc;
    }
}

// ---------------- pool reduce + glob (single block) ----------------
__global__ __launch_bounds__(256) void k_glob2(const float* __restrict__ ppart,
                                               const float* __restrict__ g1w,
                                               const float* __restrict__ g1b,
                                               const float* __restrict__ g2w,
                                               const float* __restrict__ g2b,
                                               float* __restrict__ glob) {
    __shared__ float pl[256], hid[256];
    int t = threadIdx.x;
    for (int b = 0; b < BB; b++) {
        float s = 0.f;
        for (int p = 0; p < 128; p++) s += ppart[((size_t)b * 128 + p) * 256 + t];
        pl[t] = s * (2.f / 16384.f);
        __syncthreads();
        float acc = g1b[t];
        for (int k = 0; k < 256; k++) acc += pl[k] * g1w[k * 256 + t];
        hid[t] = fmaxf(acc, 0.f);
        __syncthreads();
        float a2 = g2b[t];
        for (int k = 0; k < 256; k++) a2 += hid[k] * g2w[k * 256 + t];
        glob[b * 256 + t] = a2;
        __syncthreads();
    }
}

// ---------------- fused mid pipeline: s -> t -> fre -> K,V  (one kernel) ----------------
// 512 blocks x 64 rows. 256 thr, 4 waves (2 wrow x 2 wcol), wave = 32 rows x 128 cols.
// t / fre live in a 32KB XOR-swizzled LDS tile; B panels k-grouped, DMA-staged.
__global__ __launch_bounds__(256, 3) void k_mid(const float* __restrict__ key,
                                                const ushort* __restrict__ l1t,
                                                const ushort* __restrict__ l2t,
                                                const ushort* __restrict__ kwt,
                                                const ushort* __restrict__ vwt,
                                                const float* __restrict__ l1b,
                                                const float* __restrict__ l2b,
                                                const float* __restrict__ kbias,
                                                const float* __restrict__ vbias,
                                                const float* __restrict__ glob,
                                                ushort* __restrict__ Km,
                                                ushort* __restrict__ Vn) {
    __shared__ __align__(16) ushort smem[26624];  // tile 32KB | As 4KB | Bs 16KB
    ushort* tile = smem;            // [64][256] bf16, byte ^= (row&7)<<4
    ushort* As = smem + 16384;      // [4][64][8] k-grouped
    ushort* Bs = smem + 18432;      // [4][256][8] k-grouped

    const int tid = threadIdx.x;
    const int lane = tid & 63;
    const int wid = tid >> 6;
    const int wrow = wid >> 1, wcol = wid & 1;
    const int R0 = blockIdx.x * 64;
    const int b = R0 >> 14;
    const int l15 = lane & 15, l4 = lane >> 4;

    // A-gather geometry (GEMM1)
    const int srow = tid & 63, skq = tid >> 6;
    size_t agbase;
    {
        int R = R0 + srow;
        int rr = R & 16383;
        int ii = rr >> 7, jj = rr & 127;
        agbase = ((size_t)b * 65536 + (size_t)(2 * ii + 1) * 256 + (2 * jj + 1)) * 256 + skq * 8;
    }

    f32x4 acc[2][8];

    // ---------------- GEMM1: t = relu(s @ l1 + l1b) ----------------
#pragma unroll
    for (int m = 0; m < 2; m++)
#pragma unroll
        for (int n = 0; n < 8; n++) acc[m][n] = (f32x4){0.f, 0.f, 0.f, 0.f};

    for (int ks = 0; ks < 8; ks++) {
        // stage A: gathered key rows, x2, -> bf16 (k-grouped)
        float4 f0 = *(const float4*)(key + agbase + (size_t)ks * 32);
        float4 f1 = *(const float4*)(key + agbase + (size_t)ks * 32 + 4);
        uint4 pk = {cvtpk(f0.x * 2.f, f0.y * 2.f), cvtpk(f0.z * 2.f, f0.w * 2.f),
                    cvtpk(f1.x * 2.f, f1.y * 2.f), cvtpk(f1.z * 2.f, f1.w * 2.f)};
        *(uint4*)((char*)As + skq * 1024 + srow * 16) = pk;
        // stage B panel (16KB DMA)
        {
            const char* pan = (const char*)l1t + (size_t)ks * 16384;
            char* dst = (char*)Bs + wid * 4096;
#pragma unroll
            for (int i = 0; i < 4; i++)
                gload16(pan + wid * 4096 + i * 1024 + lane * 16, dst + i * 1024);
        }
        __syncthreads();
        short8v a[2], bf[8];
#pragma unroll
        for (int m = 0; m < 2; m++)
            a[m] = *(const short8v*)((const char*)As + l4 * 1024 + (wrow * 32 + m * 16 + l15) * 16);
#pragma unroll
        for (int n = 0; n < 8; n++)
            bf[n] = *(const short8v*)((const char*)Bs + l4 * 4096 + (wcol * 128 + n * 16 + l15) * 16);
#pragma unroll
        for (int m = 0; m < 2; m++)
#pragma unroll
            for (int n = 0; n < 8; n++)
                acc[m][n] = __builtin_amdgcn_mfma_f32_16x16x32_bf16(a[m], bf[n], acc[m][n], 0, 0, 0);
        __syncthreads();
    }
    // t -> tile (relu, bf16, swizzled)
#pragma unroll
    for (int m = 0; m < 2; m++) {
#pragma unroll
        for (int n = 0; n < 8; n++) {
            int col = wcol * 128 + n * 16 + l15;
            float bias = l1b[col];
#pragma unroll
            for (int r = 0; r < 4; r++) {
                int row = wrow * 32 + m * 16 + l4 * 4 + r;
                float x = acc[m][n][r] + bias;
                int byte = (row * 512 + col * 2) ^ ((row & 7) << 4);
                *(ushort*)((char*)tile + byte) = f2bf(fmaxf(x, 0.f));
            }
        }
    }

    // ---------------- GEMM2: fre = sigmoid(t @ l2 + l2b + glob)*high + low ----------------
#pragma unroll
    for (int m = 0; m < 2; m++)
#pragma unroll
        for (int n = 0; n < 8; n++) acc[m][n] = (f32x4){0.f, 0.f, 0.f, 0.f};

    for (int ks = 0; ks < 8; ks++) {
        {
            const char* pan = (const char*)l2t + (size_t)ks * 16384;
            char* dst = (char*)Bs + wid * 4096;
#pragma unroll
            for (int i = 0; i < 4; i++)
                gload16(pan + wid * 4096 + i * 1024 + lane * 16, dst + i * 1024);
        }
        __syncthreads();
        short8v a[2], bf[8];
#pragma unroll
        for (int m = 0; m < 2; m++) {
            int row = wrow * 32 + m * 16 + l15;
            int byte = (row * 512 + ks * 64 + l4 * 16) ^ ((row & 7) << 4);
            a[m] = *(const short8v*)((const char*)tile + byte);
        }
#pragma unroll
        for (int n = 0; n < 8; n++)
            bf[n] = *(const short8v*)((const char*)Bs + l4 * 4096 + (wcol * 128 + n * 16 + l15) * 16);
#pragma unroll
        for (int m = 0; m < 2; m++)
#pragma unroll
            for (int n = 0; n < 8; n++)
                acc[m][n] = __builtin_amdgcn_mfma_f32_16x16x32_bf16(a[m], bf[n], acc[m][n], 0, 0, 0);
        __syncthreads();
    }
    // fre epilogue -> tile (overwrite t)
#pragma unroll
    for (int m = 0; m < 2; m++) {
#pragma unroll
        for (int n = 0; n < 8; n++) {
            int col = wcol * 128 + n * 16 + l15;
            float bias = l2b[col] + glob[b * 256 + col];
#pragma unroll
            for (int r = 0; r < 4; r++) {
                int row = wrow * 32 + m * 16 + l4 * 4 + r;
                int rr = (R0 + row) & 16383;
                int ii = rr >> 7, jj = rr & 127;
                size_t kb = ((size_t)b * 65536 + (size_t)(2 * ii) * 256 + 2 * jj) * 256 + col;
                float ka = key[kb];
                float kb2 = key[kb + 256];
                float kc2 = key[kb + 65536];
                float kd2 = key[kb + 65536 + 256];
                float low = 0.5f * (ka + kb2 + kc2 + kd2);
                float high = 0.5f * (3.f * kd2 - ka - kb2 - kc2);
                float x = acc[m][n][r] + bias;
                float wei = 1.f / (1.f + __expf(-x));
                int byte = (row * 512 + col * 2) ^ ((row & 7) << 4);
                *(ushort*)((char*)tile + byte) = f2bf(wei * high + low);
            }
        }
    }

    // ---------------- GEMM3: Km = elu(fre @ kw + kb) + 1 ----------------
#pragma unroll
    for (int m = 0; m < 2; m++)
#pragma unroll
        for (int n = 0; n < 8; n++) acc[m][n] = (f32x4){0.f, 0.f, 0.f, 0.f};

    for (int ks = 0; ks < 8; ks++) {
        {
            const char* pan = (const char*)kwt + (size_t)ks * 16384;
            char* dst = (char*)Bs + wid * 4096;
#pragma unroll
            for (int i = 0; i < 4; i++)
                gload16(pan + wid * 4096 + i * 1024 + lane * 16, dst + i * 1024);
        }
        __syncthreads();
        short8v a[2], bf[8];
#pragma unroll
        for (int m = 0; m < 2; m++) {
            int row = wrow * 32 + m * 16 + l15;
            int byte = (row * 512 + ks * 64 + l4 * 16) ^ ((row & 7) << 4);
            a[m] = *(const short8v*)((const char*)tile + byte);
        }
#pragma unroll
        for (int n = 0; n < 8; n++)
            bf[n] = *(const short8v*)((const char*)Bs + l4 * 4096 + (wcol * 128 + n * 16 + l15) * 16);
#pragma unroll
        for (int m = 0; m < 2; m++)
#pragma unroll
            for (int n = 0; n < 8; n++)
                acc[m][n] = __builtin_amdgcn_mfma_f32_16x16x32_bf16(a[m], bf[n], acc[m][n], 0, 0, 0);
        __syncthreads();
    }
#pragma unroll
    for (int m = 0; m < 2; m++) {
#pragma unroll
        for (int n = 0; n < 8; n++) {
            int col = wcol * 128 + n * 16 + l15;
            float bias = kbias[col];
#pragma unroll
            for (int r = 0; r < 4; r++) {
                int row = wrow * 32 + m * 16 + l4 * 4 + r;
                float x = acc[m][n][r] + bias;
                Km[(size_t)(R0 + row) * 256 + col] = f2bf((x > 0.f) ? x + 1.f : __expf(x));
            }
        }
    }

    // ---------------- GEMM4: Vn = fre @ vw + vb ----------------
#pragma unroll
    for (int m = 0; m < 2; m++)
#pragma unroll
        for (int n = 0; n < 8; n++) acc[m][n] = (f32x4){0.f, 0.f, 0.f, 0.f};

    for (int ks = 0; ks < 8; ks++) {
        {
            const char* pan = (const char*)vwt + (size_t)ks * 16384;
            char* dst = (char*)Bs + wid * 4096;
#pragma unroll
            for (int i = 0; i < 4; i++)
                gload16(pan + wid * 4096 + i * 1024 + lane * 16, dst + i * 1024);
        }
        __syncthreads();
        short8v a[2], bf[8];
#pragma unroll
        for (int m = 0; m < 2; m++) {
            int row = wrow * 32 + m * 16 + l15;
            int byte = (row * 512 + ks * 64 + l4 * 16) ^ ((row & 7) << 4);
            a[m] = *(const short8v*)((const char*)tile + byte);
        }
#pragma unroll
        for (int n = 0; n < 8; n++)
            bf[n] = *(const short8v*)((const char*)Bs + l4 * 4096 + (wcol * 128 + n * 16 + l15) * 16);
#pragma unroll
        for (int m = 0; m < 2; m++)
#pragma unroll
            for (int n = 0; n < 8; n++)
                acc[m][n] = __builtin_amdgcn_mfma_f32_16x16x32_bf16(a[m], bf[n], acc[m][n], 0, 0, 0);
        __syncthreads();
    }
#pragma unroll
    for (int m = 0; m < 2; m++) {
#pragma unroll
        for (int n = 0; n < 8; n++) {
            int col = wcol * 128 + n * 16 + l15;
            float bias = vbias[col];
#pragma unroll
            for (int r = 0; r < 4; r++) {
                int row = wrow * 32 + m * 16 + l4 * 4 + r;
                Vn[(size_t)(R0 + row) * 256 + col] = f2bf(acc[m][n][r] + bias);
            }
        }
    }
}

// ---------------- KV partials (bf16 in) ----------------
__global__ __launch_bounds__(256) void k_kv_part(const ushort* __restrict__ Km,
                                                 const ushort* __restrict__ Vn,
                                                 float* __restrict__ kvp,
                                                 float* __restrict__ ksp) {
    __shared__ float Kl[8][33];
    __shared__ float Vl[8][33];
    int t = threadIdx.x;
    int c = blockIdx.x & 31, h = (blockIdx.x >> 5) & 7, b = blockIdx.x >> 8;
    int d = t >> 3, vq = (t & 7) * 4;
    int lr = t >> 5, lc = t & 31;
    float acc0 = 0, acc1 = 0, acc2 = 0, acc3 = 0, ks = 0;
    size_t rowbase = (size_t)b * 16384 + (size_t)c * 512;
    for (int s0 = 0; s0 < 512; s0 += 8) {
        size_t idx = (rowbase + s0 + lr) * 256 + h * 32 + lc;
        Kl[lr][lc] = bf2f(Km[idx]);
        Vl[lr][lc] = bf2f(Vn[idx]);
        __syncthreads();
#pragma unroll
        for (int rr = 0; rr < 8; rr++) {
            float kd = Kl[rr][d];
            acc0 += kd * Vl[rr][vq];
            acc1 += kd * Vl[rr][vq + 1];
            acc2 += kd * Vl[rr][vq + 2];
            acc3 += kd * Vl[rr][vq + 3];
            ks += kd;
        }
        __syncthreads();
    }
    size_t ob = ((size_t)(b * 8 + h) * 32 + c) * 1024 + d * 32 + vq;
    kvp[ob] = acc0; kvp[ob + 1] = acc1; kvp[ob + 2] = acc2; kvp[ob + 3] = acc3;
    if ((t & 7) == 0) ksp[((b * 8 + h) * 32 + c) * 32 + d] = ks;
}

// ---------------- KV reduce -> bf16 augmented B^T: KVt[bh][48][32] ----------------
__global__ __launch_bounds__(256) void k_kv_reduce(const float* __restrict__ kvp,
                                                   const float* __restrict__ ksp,
                                                   ushort* __restrict__ kvt) {
    int bh = blockIdx.x, t = threadIdx.x;
    for (int e = t; e < 1024; e += 256) {
        float s = 0.f;
        for (int cc = 0; cc < 32; cc++) s += kvp[((size_t)bh * 32 + cc) * 1024 + e];
        int d = e >> 5, v = e & 31;
        kvt[((size_t)bh * 48 + v) * 32 + d] = f2bf(s);
    }
    if (t < 32) {
        float s = 0.f;
        for (int cc = 0; cc < 32; cc++) s += ksp[(bh * 32 + cc) * 32 + t];
        kvt[((size_t)bh * 48 + 32) * 32 + t] = f2bf(s);
    }
    for (int z = t; z < 480; z += 256) kvt[(size_t)bh * 48 * 32 + 33 * 32 + z] = 0;
}

// ---------------- MFMA q-GEMM (BM=128 BN=256 BK=64) + linear-attn epilogue ----------------
// 512 threads, 8 waves (2 wrow x 4 wcol), each wave 64x64. k-grouped LDS, conflict-free frags.
__global__ __launch_bounds__(512, 4) void k_qattn_mfma(const float* __restrict__ query,
                                                       const ushort* __restrict__ wfp,
                                                       const float* __restrict__ qb,
                                                       const ushort* __restrict__ kvt,
                                                       float* __restrict__ Out) {
    __shared__ __align__(16) ushort smem[32768];  // As 16KB | Bs 32KB; Q-tile overlays 64KB
    ushort* As = smem;          // [8][128][8] k-grouped
    ushort* Bs = smem + 8192;   // [8][256][8] k-grouped

    const int tid = threadIdx.x;
    const int lane = tid & 63;
    const int wid = tid >> 6;            // 0..7
    const int wrow = wid >> 2, wcol = wid & 3;
    const int R0 = blockIdx.x * 128;
    const int l15 = lane & 15, l4 = lane >> 4;

    const int srow = tid & 127;          // staging row
    const int khalf = tid >> 7;          // 0..3: which 16-float chunk of the 64-k step
    const size_t agbase = (size_t)(R0 + srow) * 512 + khalf * 16;

    f32x4 acc[4][4];
#pragma unroll
    for (int i = 0; i < 4; i++)
#pragma unroll
        for (int j = 0; j < 4; j++) acc[i][j] = (f32x4){0.f, 0.f, 0.f, 0.f};

    for (int ks = 0; ks < 8; ks++) {
        // stage A: 64B fp32 per thread -> 32B bf16, two k-groups
        {
            const float* qp = query + agbase + (size_t)ks * 64;
            float4 f0 = *(const float4*)(qp);
            float4 f1 = *(const float4*)(qp + 4);
            float4 f2 = *(const float4*)(qp + 8);
            float4 f3 = *(const float4*)(qp + 12);
            uint4 lo = {cvtpk(f0.x, f0.y), cvtpk(f0.z, f0.w), cvtpk(f1.x, f1.y), cvtpk(f1.z, f1.w)};
            uint4 hi = {cvtpk(f2.x, f2.y), cvtpk(f2.z, f2.w), cvtpk(f3.x, f3.y), cvtpk(f3.z, f3.w)};
            *(uint4*)((char*)As + (khalf * 2) * 2048 + srow * 16) = lo;
            *(uint4*)((char*)As + (khalf * 2 + 1) * 2048 + srow * 16) = hi;
        }
        // stage B: 32KB k-grouped panel, pure DMA (8 waves x 1KB x 4 rounds)
        {
            const char* pan = (const char*)wfp + (size_t)ks * 32768;
#pragma unroll
            for (int i = 0; i < 4; i++)
                gload16(pan + i * 8192 + wid * 1024 + lane * 16, (char*)Bs + i * 8192 + wid * 1024);
        }
        __syncthreads();

#pragma unroll
        for (int sub = 0; sub < 2; sub++) {
            short8v a[4], bf[4];
#pragma unroll
            for (int m = 0; m < 4; m++)
                a[m] = *(const short8v*)((const char*)As + (sub * 4 + l4) * 2048 + (wrow * 64 + m * 16 + l15) * 16);
#pragma unroll
            for (int n = 0; n < 4; n++)
                bf[n] = *(const short8v*)((const char*)Bs + (sub * 4 + l4) * 4096 + (wcol * 64 + n * 16 + l15) * 16);
#pragma unroll
            for (int m = 0; m < 4; m++)
#pragma unroll
                for (int n = 0; n < 4; n++)
                    acc[m][n] = __builtin_amdgcn_mfma_f32_16x16x32_bf16(a[m], bf[n], acc[m][n], 0, 0, 0);
        }
        __syncthreads();
    }

    // Q = elu(x+qb)+1 -> per-wave Qs region [64][64] bf16, XOR-swizzled
    float qbv[4];
#pragma unroll
    for (int n = 0; n < 4; n++) qbv[n] = qb[wcol * 64 + n * 16 + l15];
#pragma unroll
    for (int m = 0; m < 4; m++) {
#pragma unroll
        for (int n = 0; n < 4; n++) {
#pragma unroll
            for (int r = 0; r < 4; r++) {
                int rl = m * 16 + l4 * 4 + r;
                int cl = n * 16 + l15;
                float x = acc[m][n][r] + qbv[n];
                float q = x > 0.f ? x + 1.f : __expf(x);
                int byte = wid * 8192 + ((rl * 128 + cl * 2) ^ ((rl & 7) << 4));
                *(ushort*)((char*)smem + byte) = f2bf(q);
            }
        }
    }
    __syncthreads();

    // attention epilogue: wave's 2 heads; O = Q_h @ KV_aug (cols 0..31 KV, col 32 Ksum)
    const int bb = R0 >> 16;
#pragma unroll
    for (int hi = 0; hi < 2; hi++) {
        int h = wcol * 2 + hi;
        int bh = bb * 8 + h;
        const ushort* kb = kvt + (size_t)bh * 48 * 32;
        short8v bk0 = *(const short8v*)(kb + (0 * 16 + l15) * 32 + l4 * 8);
        short8v bk1 = *(const short8v*)(kb + (1 * 16 + l15) * 32 + l4 * 8);
        short8v bkz = *(const short8v*)(kb + (2 * 16 + l15) * 32 + l4 * 8);
#pragma unroll
        for (int m = 0; m < 4; m++) {
            int rl = m * 16 + l15;
            int byte = wid * 8192 + ((rl * 128 + hi * 64 + l4 * 16) ^ ((rl & 7) << 4));
            short8v aq = *(const short8v*)((const char*)smem + byte);
            f32x4 zero = (f32x4){0.f, 0.f, 0.f, 0.f};
            f32x4 o0 = __builtin_amdgcn_mfma_f32_16x16x32_bf16(aq, bk0, zero, 0, 0, 0);
            f32x4 o1 = __builtin_amdgcn_mfma_f32_16x16x32_bf16(aq, bk1, zero, 0, 0, 0);
            f32x4 oz = __builtin_amdgcn_mfma_f32_16x16x32_bf16(aq, bkz, zero, 0, 0, 0);
#pragma unroll
            for (int r = 0; r < 4; r++) {
                float z = __shfl(oz[r], (lane & 48));
                float sc = 1.f / (z + 1e-6f);
                int grow = R0 + wrow * 64 + m * 16 + l4 * 4 + r;
                int gcol = wcol * 64 + hi * 32 + l15;
                Out[(size_t)grow * 256 + gcol] = o0[r] * sc;
                Out[(size_t)grow * 256 + gcol + 16] = o1[r] * sc;
            }
        }
    }
}

extern "C" void kernel_launch(void* const* d_in, const int* in_sizes, int n_in,
                              void* d_out, int out_size, void* d_ws, size_t ws_size,
                              hipStream_t stream) {
    const float* query = (const float*)d_in[0];
    const float* key = (const float*)d_in[1];
    // d_in[2] = value: only its shape is used by the reference — never read.
    const float* mh = (const float*)d_in[3];
    const float* q_w = (const float*)d_in[4];
    const float* q_b = (const float*)d_in[5];
    const float* k_w = (const float*)d_in[6];
    const float* k_b = (const float*)d_in[7];
    const float* v_w = (const float*)d_in[8];
    const float* v_b = (const float*)d_in[9];
    const float* l1_w = (const float*)d_in[10];
    const float* l1_b = (const float*)d_in[11];
    const float* l2_w = (const float*)d_in[12];
    const float* l2_b = (const float*)d_in[13];
    const float* g1_w = (const float*)d_in[14];
    const float* g1_b = (const float*)d_in[15];
    const float* g2_w = (const float*)d_in[16];
    const float* g2_b = (const float*)d_in[17];

    float* out = (float*)d_out;
    float* ws = (float*)d_ws;

    float* ppart = ws + WS_PPART;
    float* glob = ws + WS_GLOB;
    float* kvp = ws + WS_KVP;
    float* ksp = ws + WS_KSP;
    ushort* kvt = (ushort*)(ws + WS_KVT);
    ushort* wfp = (ushort*)(ws + WS_WFP);
    ushort* l1t = (ushort*)(ws + WS_L1T);
    ushort* l2t = (ushort*)(ws + WS_L2T);
    ushort* kwt = (ushort*)(ws + WS_KWT);
    ushort* vwt = (ushort*)(ws + WS_VWT);

    // Km/Vn live inside d_out (qattn overwrites everything at the end)
    ushort* Km = (ushort*)out;                     // 32768x256 bf16
    ushort* Vn = (ushort*)(out + 4194304);         // 32768x256 bf16

    k_prep<<<1792, 256, 0, stream>>>(l1_w, l2_w, k_w, v_w, mh, q_w, key,
                                     l1t, l2t, kwt, vwt, wfp, ppart);
    k_glob2<<<1, 256, 0, stream>>>(ppart, g1_w, g1_b, g2_w, g2_b, glob);

    k_mid<<<512, 256, 0, stream>>>(key, l1t, l2t, kwt, vwt,
                                   l1_b, l2_b, k_b, v_b, glob, Km, Vn);

    k_kv_part<<<512, 256, 0, stream>>>(Km, Vn, kvp, ksp);
    k_kv_reduce<<<16, 256, 0, stream>>>(kvp, ksp, kvt);

    k_qattn_mfma<<<1024, 512, 0, stream>>>(query, wfp, q_b, kvt, out);
}